// Round 13
// baseline (43.996 us; speedup 1.0000x reference)
//
#include <hip/hip_runtime.h>
#include <hip/hip_bf16.h>

#define S_LEN 2048
#define DH    64
#define NBH   32
#define KSCALE 0.1803368801111f  /* (1/8) * log2(e) */
#define LN2    0.6931471805599453f
#define MB2    4.0f              /* static max bias, log2 domain */

typedef short v4s __attribute__((ext_vector_type(4)));
typedef short v8s __attribute__((ext_vector_type(8)));
typedef float v4f __attribute__((ext_vector_type(4)));

__device__ __forceinline__ unsigned short f2bf(float f){
  union { float f; unsigned int u; } v; v.f = f;
  return (unsigned short)((v.u + 0x7FFFu + ((v.u >> 16) & 1u)) >> 16);
}

__device__ __forceinline__ void gld16(void* lds, const void* g){
  __builtin_amdgcn_global_load_lds(
      (const __attribute__((address_space(1))) unsigned int*)g,
      (__attribute__((address_space(3))) unsigned int*)lds, 16, 0, 0);
}

// ---------------- pre-pass: K,V fp32 -> bf16 in MFMA-fragment order ----------
// Kf chunk layout (per bh, per 64-row tile t), 8KB:
//   byte (kb*2+h)*1024 + l*16 + j*2  =  K[t*64 + kb*16 + (l&15)][h*32 + (l>>4)*8 + j]
// Vf chunk layout v2 (conflict-free b128 reads), 8KB:
//   byte (kb*2+dp)*1024 + l*16 + e*8 + j*2
//     = V[t*64 + kb*16 + (l>>4)*4 + j][(dp*2+e)*16 + (l&15)]
__global__ __launch_bounds__(256) void prep(const float* __restrict__ K,
                                            const float* __restrict__ V,
                                            unsigned short* __restrict__ Kf,
                                            unsigned short* __restrict__ Vf){
  __shared__ unsigned short s[64 * 72];
  const int t   = blockIdx.x;
  const int bh  = blockIdx.y;
  const int tid = threadIdx.x;

  // ---- K phase ----
  const float* Ksrc = K + ((size_t)bh * S_LEN + t * 64) * DH;
  #pragma unroll
  for (int i = 0; i < 4; ++i){
    int f = tid + i * 256;                 // float4 index
    float4 v = ((const float4*)Ksrc)[f];
    int row = f >> 4, col = (f & 15) * 4;
    ushort4 o; o.x = f2bf(v.x); o.y = f2bf(v.y); o.z = f2bf(v.z); o.w = f2bf(v.w);
    *(ushort4*)(&s[row * 72 + col]) = o;
  }
  __syncthreads();
  unsigned short* KfT = Kf + ((size_t)bh * 32 + t) * 4096;
  #pragma unroll
  for (int i = 0; i < 2; ++i){
    int item = tid + i * 256;
    int c = item >> 6, l = item & 63;
    int kb = c >> 1, h = c & 1;
    v8s frag = *(const v8s*)(&s[(kb * 16 + (l & 15)) * 72 + h * 32 + (l >> 4) * 8]);
    *(v8s*)(&KfT[c * 512 + l * 8]) = frag;
  }
  __syncthreads();

  // ---- V phase (transposed into LDS) ----
  const float* Vsrc = V + ((size_t)bh * S_LEN + t * 64) * DH;
  #pragma unroll
  for (int i = 0; i < 4; ++i){
    int f = tid + i * 256;
    float4 v = ((const float4*)Vsrc)[f];
    int k = f >> 4, d = (f & 15) * 4;
    s[(d + 0) * 72 + k] = f2bf(v.x);
    s[(d + 1) * 72 + k] = f2bf(v.y);
    s[(d + 2) * 72 + k] = f2bf(v.z);
    s[(d + 3) * 72 + k] = f2bf(v.w);
  }
  __syncthreads();
  unsigned short* VfT = Vf + ((size_t)bh * 32 + t) * 4096;
  #pragma unroll
  for (int i = 0; i < 2; ++i){
    int item = tid + i * 256;
    int c = item >> 6, l = item & 63;     // c = kb*2 + dp
    int kb = c >> 1, dp = c & 1;
    int kk = kb * 16 + (l >> 4) * 4;
    v4s a = *(const v4s*)(&s[((dp * 2 + 0) * 16 + (l & 15)) * 72 + kk]);
    v4s b = *(const v4s*)(&s[((dp * 2 + 1) * 16 + (l & 15)) * 72 + kk]);
    v8s fr; fr[0]=a[0]; fr[1]=a[1]; fr[2]=a[2]; fr[3]=a[3];
            fr[4]=b[0]; fr[5]=b[1]; fr[6]=b[2]; fr[7]=b[3];
    *(v8s*)(&VfT[c * 512 + l * 8]) = fr;
  }
}

// ---------------- main flash-attention forward ----------------
// 1024 blocks x 512 thr (8 waves), __launch_bounds__(512,4): 2 blocks/CU
// (64KB LDS each), 16 waves/CU. K-STEP = 128 (two prep 64-tiles per stage):
// halves the number of barrier intervals vs round 12 (34 steps/CU, balanced).
// 4-phase heavy-first qt map: o=bid>>5, a=o&7; r=o>>3:
//   r0: qt=31-a  r1: qt=16+a  r2: qt=15-a  r3: qt=a
// -> every CU's 4 sequential blocks sum to exactly 34 128-k steps; first
// 512 bids are the heavy half. bh=bid&31 keeps same-bh blocks on one XCD.
// Wave (kq=w>>2, qs=w&3): q-subtile qs (16 rows) x 64-k half kq of each
// 128-k stage. Static-max softmax is k-linear -> 2-way (kq) O/l reduction
// once at the end in the drained staging buffers.
// S^T = K*Q^T (16x16x32): C/D col=lane&15=q, row=4g+r=k-local.
// O^T = V^T*P^T (16x16x16 bf16_1k): B-frag == S^T C-frag -> P stays in regs.
__global__ __launch_bounds__(512, 4) void fa_fwd(
    const float* __restrict__ Q,
    const unsigned short* __restrict__ Kf,
    const unsigned short* __restrict__ Vf,
    float* __restrict__ O, float* __restrict__ L)
{
  __shared__ __align__(16) char smem[2][32768];   // [buf][ K 16KB | V 16KB ]

  const int tid  = threadIdx.x;
  const int w    = tid >> 6;
  const int lane = tid & 63;
  const int lq   = lane & 15;
  const int g    = lane >> 4;
  const int kq   = w >> 2;                 // 64-k half (0/1)
  const int qs   = w & 3;                  // q-subtile (0..3)
  const int bid  = blockIdx.x;
  const int o    = bid >> 5;
  const int r4   = o >> 3, a = o & 7;
  const int qt   = (r4 == 0) ? 31 - a : (r4 == 1) ? 16 + a
                 : (r4 == 2) ? 15 - a : a;
  const int bh   = bid & 31;
  const int M2   = (qt >> 1) + 1;          // 128-k steps
  const int qw0  = qt * 64 + qs * 16;      // my 16 q-rows base

  const unsigned short* KfB = Kf + (size_t)bh * 32 * 4096;
  const unsigned short* VfB = Vf + (size_t)bh * 32 * 4096;

  auto issue = [&](int t, char* buf){
    const size_t base = (size_t)(2 * t) * 4096;
    gld16(buf +         tid * 16, KfB + base +        tid * 8);
    gld16(buf +  8192 + tid * 16, KfB + base + 4096 + tid * 8);
    gld16(buf + 16384 + tid * 16, VfB + base +        tid * 8);
    gld16(buf + 24576 + tid * 16, VfB + base + 4096 + tid * 8);
  };

  // hoist Q fragment (one 16-row subtile), pre-scaled, fp32 -> bf16
  v8s qf[2];
  {
    const float* qp = Q + (size_t)(bh * S_LEN + qw0 + lq) * DH + g * 8;
    #pragma unroll
    for (int h = 0; h < 2; ++h){
      float4 aa = *(const float4*)(qp + h * 32);
      float4 bb = *(const float4*)(qp + h * 32 + 4);
      v8s qv;
      qv[0]=(short)f2bf(aa.x*KSCALE); qv[1]=(short)f2bf(aa.y*KSCALE);
      qv[2]=(short)f2bf(aa.z*KSCALE); qv[3]=(short)f2bf(aa.w*KSCALE);
      qv[4]=(short)f2bf(bb.x*KSCALE); qv[5]=(short)f2bf(bb.y*KSCALE);
      qv[6]=(short)f2bf(bb.z*KSCALE); qv[7]=(short)f2bf(bb.w*KSCALE);
      qf[h] = qv;
    }
  }

  issue(0, smem[0]);   // prologue

  const v4f zero  = {0.f, 0.f, 0.f, 0.f};
  const v4f minit = {-MB2, -MB2, -MB2, -MB2};
  v4f acc[4];                          // [db]
  acc[0] = zero; acc[1] = zero; acc[2] = zero; acc[3] = zero;
  float l1 = 0.f;

  for (int t = 0; t < M2; ++t){
    const int tn = (t + 1 < M2) ? t + 1 : t;
    issue(tn, smem[(t + 1) & 1]);                    // prefetch next 128-tile
    asm volatile("s_waitcnt vmcnt(4)" ::: "memory"); // current tile landed
    __builtin_amdgcn_s_barrier();
    __builtin_amdgcn_sched_barrier(0);

    const int  kstart = t * 128 + kq * 64;
    const bool lastT  = (t + 1 == M2);
    const bool live   = !lastT || (kstart <= qw0 + 15);

    if (live){
      const char* kbase = smem[t & 1] +         kq * 8192;
      const char* vbase = smem[t & 1] + 16384 + kq * 8192;

      // ---- S^T = K * Q^T for my 4 k-subblocks (16 rows each) ----
      float p4[4][4];
      __builtin_amdgcn_s_setprio(1);
      #pragma unroll
      for (int j = 0; j < 4; ++j){
        v8s kf0 = *(const v8s*)(kbase + (j * 2    ) * 1024 + lane * 16);
        v8s kf1 = *(const v8s*)(kbase + (j * 2 + 1) * 1024 + lane * 16);
        v4f st = minit;
        st = __builtin_amdgcn_mfma_f32_16x16x32_bf16(kf0, qf[0], st, 0, 0, 0);
        st = __builtin_amdgcn_mfma_f32_16x16x32_bf16(kf1, qf[1], st, 0, 0, 0);
        p4[j][0] = st[0]; p4[j][1] = st[1]; p4[j][2] = st[2]; p4[j][3] = st[3];
      }
      __builtin_amdgcn_s_setprio(0);

      if (lastT){                        // tile containing the diagonal
        #pragma unroll
        for (int j = 0; j < 4; ++j)
          #pragma unroll
          for (int r = 0; r < 4; ++r)
            if (kstart + j * 16 + g * 4 + r > qw0 + lq) p4[j][r] = -INFINITY;
      }

      // ---- P = exp2(S-4), lane-partial l, pack to bf16 ----
      v4s pf[4];
      #pragma unroll
      for (int j = 0; j < 4; ++j){
        #pragma unroll
        for (int r = 0; r < 4; ++r){
          const float pe = __builtin_amdgcn_exp2f(p4[j][r]);   // masked -> 0
          p4[j][r] = pe;
          l1 += pe;
        }
        unsigned u0, u1;
        asm("v_cvt_pk_bf16_f32 %0, %1, %2" : "=v"(u0) : "v"(p4[j][0]), "v"(p4[j][1]));
        asm("v_cvt_pk_bf16_f32 %0, %1, %2" : "=v"(u1) : "v"(p4[j][2]), "v"(p4[j][3]));
        union { unsigned u[2]; v4s s4; } P; P.u[0] = u0; P.u[1] = u1;
        pf[j] = P.s4;
      }

      // ---- O^T += V^T * P^T for my 4 k-subblocks ----
      __builtin_amdgcn_s_setprio(1);
      #pragma unroll
      for (int j = 0; j < 4; ++j){
        #pragma unroll
        for (int dp = 0; dp < 2; ++dp){
          v8s vv8 = *(const v8s*)(vbase + (j * 2 + dp) * 1024 + lane * 16);
          v4s va0 = {vv8[0], vv8[1], vv8[2], vv8[3]};
          v4s va1 = {vv8[4], vv8[5], vv8[6], vv8[7]};
          acc[dp * 2    ] = __builtin_amdgcn_mfma_f32_16x16x16bf16_1k(va0, pf[j], acc[dp * 2    ], 0, 0, 0);
          acc[dp * 2 + 1] = __builtin_amdgcn_mfma_f32_16x16x16bf16_1k(va1, pf[j], acc[dp * 2 + 1], 0, 0, 0);
        }
      }
      __builtin_amdgcn_s_setprio(0);
    }
    __builtin_amdgcn_s_barrier();
    __builtin_amdgcn_sched_barrier(0);
  }

  // ---- drain async staging writes before reusing smem as scratch ----
  asm volatile("s_waitcnt vmcnt(0)" ::: "memory");
  __builtin_amdgcn_sched_barrier(0);
  __syncthreads();

  // ---- epilogue: 2-way (kq) reduction of l and O, conflict-free layout ----
  l1 += __shfl_xor(l1, 16);
  l1 += __shfl_xor(l1, 32);

  float* Lx = (float*)(smem[1]);         // 64 floats [qs*16 + lq]
  v4f*  Ox = (v4f*)(smem[0]);            // [ (qs*4+db)*64 + lane ] 16KB
  if (kq == 1){
    if (lane < 16) Lx[qs * 16 + lane] = l1;
    #pragma unroll
    for (int db = 0; db < 4; ++db)
      Ox[(qs * 4 + db) * 64 + lane] = acc[db];
  }
  __syncthreads();
  if (kq == 0){
    const float lt   = l1 + Lx[qs * 16 + lq];
    const float invl = 1.f / lt;
    float* Ob = O + ((size_t)bh * S_LEN + qw0 + lq) * DH;
    #pragma unroll
    for (int db = 0; db < 4; ++db){
      v4f o2 = (acc[db] + Ox[(qs * 4 + db) * 64 + lane]) * invl;
      *(v4f*)(Ob + db * 16 + g * 4) = o2;
    }
    if (lane < 16)
      L[(size_t)bh * S_LEN + qw0 + lane] = logf(lt) + MB2 * LN2;
  }
}

// ---------------- naive fallback (only if ws too small) ----------------
__global__ __launch_bounds__(64) void fa_naive(
    const float* __restrict__ Q, const float* __restrict__ K,
    const float* __restrict__ V, float* __restrict__ O, float* __restrict__ L)
{
  const int q  = blockIdx.x;
  const int bh = blockIdx.y;
  const int d  = threadIdx.x;
  const float qv = Q[(size_t)(bh * S_LEN + q) * DH + d];
  float m = -INFINITY, l = 0.f, o = 0.f;
  for (int k = 0; k <= q; ++k){
    float s = qv * K[(size_t)(bh * S_LEN + k) * DH + d];
    #pragma unroll
    for (int off = 32; off > 0; off >>= 1) s += __shfl_xor(s, off);
    s *= 0.125f;
    const float mn = fmaxf(m, s);
    const float sfc = expf(m - mn);
    const float pe = expf(s - mn);
    l = l * sfc + pe;
    o = o * sfc + pe * V[(size_t)(bh * S_LEN + k) * DH + d];
    m = mn;
  }
  O[(size_t)(bh * S_LEN + q) * DH + d] = o / l;
  if (d == 0) L[(size_t)bh * S_LEN + q] = m + logf(l);
}

extern "C" void kernel_launch(void* const* d_in, const int* in_sizes, int n_in,
                              void* d_out, int out_size, void* d_ws, size_t ws_size,
                              hipStream_t stream)
{
  (void)in_sizes; (void)n_in; (void)out_size;
  const float* Q = (const float*)d_in[0];
  const float* K = (const float*)d_in[1];
  const float* V = (const float*)d_in[2];
  float* O = (float*)d_out;
  float* L = O + (size_t)NBH * S_LEN * DH;

  const size_t half = (size_t)NBH * S_LEN * DH * sizeof(unsigned short); // 8 MiB
  if (ws_size >= 2 * half){
    unsigned short* Kf = (unsigned short*)d_ws;
    unsigned short* Vf = Kf + (size_t)NBH * S_LEN * DH;
    prep<<<dim3(S_LEN / 64, NBH), 256, 0, stream>>>(K, V, Kf, Vf);
    fa_fwd<<<dim3(1024), 512, 0, stream>>>(Q, Kf, Vf, O, L);
  } else {
    fa_naive<<<dim3(S_LEN, NBH), 64, 0, stream>>>(Q, K, V, O, L);
  }
}

// Round 15
// 42.676 us; speedup vs baseline: 1.0309x; 1.0309x over previous
//
#include <hip/hip_runtime.h>
#include <hip/hip_bf16.h>

#define S_LEN 2048
#define DH    64
#define NBH   32
#define KSCALE 0.1803368801111f  /* (1/8) * log2(e) */
#define LN2    0.6931471805599453f
#define MB2    4.0f              /* static max bias, log2 domain */

typedef short v4s __attribute__((ext_vector_type(4)));
typedef short v8s __attribute__((ext_vector_type(8)));
typedef float v4f __attribute__((ext_vector_type(4)));

__device__ __forceinline__ unsigned short f2bf(float f){
  union { float f; unsigned int u; } v; v.f = f;
  return (unsigned short)((v.u + 0x7FFFu + ((v.u >> 16) & 1u)) >> 16);
}

__device__ __forceinline__ void gld16(void* lds, const void* g){
  __builtin_amdgcn_global_load_lds(
      (const __attribute__((address_space(1))) unsigned int*)g,
      (__attribute__((address_space(3))) unsigned int*)lds, 16, 0, 0);
}

// ---------------- pre-pass: K,V fp32 -> bf16 in MFMA-fragment order ----------
// Kf chunk layout (per bh, per 64-row tile t), 8KB:
//   byte (kb*2+h)*1024 + l*16 + j*2  =  K[t*64 + kb*16 + (l&15)][h*32 + (l>>4)*8 + j]
// Vf chunk layout v2 (conflict-free b128 reads), 8KB:
//   byte (kb*2+dp)*1024 + l*16 + e*8 + j*2
//     = V[t*64 + kb*16 + (l>>4)*4 + j][(dp*2+e)*16 + (l&15)]
__global__ __launch_bounds__(256) void prep(const float* __restrict__ K,
                                            const float* __restrict__ V,
                                            unsigned short* __restrict__ Kf,
                                            unsigned short* __restrict__ Vf){
  __shared__ unsigned short s[64 * 72];
  const int t   = blockIdx.x;
  const int bh  = blockIdx.y;
  const int tid = threadIdx.x;

  // ---- K phase ----
  const float* Ksrc = K + ((size_t)bh * S_LEN + t * 64) * DH;
  #pragma unroll
  for (int i = 0; i < 4; ++i){
    int f = tid + i * 256;                 // float4 index
    float4 v = ((const float4*)Ksrc)[f];
    int row = f >> 4, col = (f & 15) * 4;
    ushort4 o; o.x = f2bf(v.x); o.y = f2bf(v.y); o.z = f2bf(v.z); o.w = f2bf(v.w);
    *(ushort4*)(&s[row * 72 + col]) = o;
  }
  __syncthreads();
  unsigned short* KfT = Kf + ((size_t)bh * 32 + t) * 4096;
  #pragma unroll
  for (int i = 0; i < 2; ++i){
    int item = tid + i * 256;
    int c = item >> 6, l = item & 63;
    int kb = c >> 1, h = c & 1;
    v8s frag = *(const v8s*)(&s[(kb * 16 + (l & 15)) * 72 + h * 32 + (l >> 4) * 8]);
    *(v8s*)(&KfT[c * 512 + l * 8]) = frag;
  }
  __syncthreads();

  // ---- V phase (transposed into LDS) ----
  const float* Vsrc = V + ((size_t)bh * S_LEN + t * 64) * DH;
  #pragma unroll
  for (int i = 0; i < 4; ++i){
    int f = tid + i * 256;
    float4 v = ((const float4*)Vsrc)[f];
    int k = f >> 4, d = (f & 15) * 4;
    s[(d + 0) * 72 + k] = f2bf(v.x);
    s[(d + 1) * 72 + k] = f2bf(v.y);
    s[(d + 2) * 72 + k] = f2bf(v.z);
    s[(d + 3) * 72 + k] = f2bf(v.w);
  }
  __syncthreads();
  unsigned short* VfT = Vf + ((size_t)bh * 32 + t) * 4096;
  #pragma unroll
  for (int i = 0; i < 2; ++i){
    int item = tid + i * 256;
    int c = item >> 6, l = item & 63;     // c = kb*2 + dp
    int kb = c >> 1, dp = c & 1;
    int kk = kb * 16 + (l >> 4) * 4;
    v4s a = *(const v4s*)(&s[((dp * 2 + 0) * 16 + (l & 15)) * 72 + kk]);
    v4s b = *(const v4s*)(&s[((dp * 2 + 1) * 16 + (l & 15)) * 72 + kk]);
    v8s fr; fr[0]=a[0]; fr[1]=a[1]; fr[2]=a[2]; fr[3]=a[3];
            fr[4]=b[0]; fr[5]=b[1]; fr[6]=b[2]; fr[7]=b[3];
    *(v8s*)(&VfT[c * 512 + l * 8]) = fr;
  }
}

// ---------------- main flash-attention forward ----------------
// Round-12 passing skeleton + T4 pipeline deepening: THREE LDS buffers,
// prefetch tile t+2, entry wait vmcnt(4) -> 2 tiles stay in flight across
// 2 barrier pairs (m218/m233: counted-vmcnt amortizes the 2-phase stall).
// All fences identical to round 12 (setprio wrappers, sched_barrier at
// entry/exit only) -- r8/r14 showed unfenced variants miscompile/race.
// Heavy-first balanced qt map (o=bid>>5, a=o&7, r=o>>3):
//   r0: qt=31-a  r1: qt=16+a  r2: qt=15-a  r3: qt=a   (per-CU sum 66)
// bh=bid&31 keeps same-bh blocks on one XCD (K/V L2-resident).
// Wave (kq=w>>2, qs=w&3): q-subtile qs (16 rows) x k-half kq of each 64-k
// tile; static-max softmax is k-linear -> 2-way (kq) O/l reduction at end.
// S^T = K*Q^T (16x16x32): C/D col=lane&15=q, row=4g+r=k-local.
// O^T = V^T*P^T (16x16x16 bf16_1k): B-frag == S^T C-frag -> P stays in regs.
__global__ __launch_bounds__(512, 6) void fa_fwd(
    const float* __restrict__ Q,
    const unsigned short* __restrict__ Kf,
    const unsigned short* __restrict__ Vf,
    float* __restrict__ O, float* __restrict__ L)
{
  __shared__ __align__(16) char smem[3][16384];   // [buf][ K 8KB | V 8KB ]

  const int tid  = threadIdx.x;
  const int w    = tid >> 6;
  const int lane = tid & 63;
  const int lq   = lane & 15;
  const int g    = lane >> 4;
  const int kq   = w >> 2;                 // k-half (0/1)
  const int qs   = w & 3;                  // q-subtile (0..3)
  const int bid  = blockIdx.x;
  const int o    = bid >> 5;
  const int r4   = o >> 3, a = o & 7;
  const int qt   = (r4 == 0) ? 31 - a : (r4 == 1) ? 16 + a
                 : (r4 == 2) ? 15 - a : a;          // heavy-first, sum 66/CU
  const int bh   = bid & 31;
  const int M    = qt + 1;                 // k-tiles for this q-tile
  const int qw0  = qt * 64 + qs * 16;

  const unsigned short* KfB = Kf + (size_t)bh * 32 * 4096;
  const unsigned short* VfB = Vf + (size_t)bh * 32 * 4096;

  auto issue = [&](int t, char* buf){
    gld16(buf +        tid * 16, KfB + (size_t)t * 4096 + tid * 8);
    gld16(buf + 8192 + tid * 16, VfB + (size_t)t * 4096 + tid * 8);
  };

  // hoist Q fragment (one 16-row subtile), pre-scaled, fp32 -> bf16
  v8s qf[2];
  {
    const float* qp = Q + (size_t)(bh * S_LEN + qw0 + lq) * DH + g * 8;
    #pragma unroll
    for (int h = 0; h < 2; ++h){
      float4 aa = *(const float4*)(qp + h * 32);
      float4 bb = *(const float4*)(qp + h * 32 + 4);
      v8s qv;
      qv[0]=(short)f2bf(aa.x*KSCALE); qv[1]=(short)f2bf(aa.y*KSCALE);
      qv[2]=(short)f2bf(aa.z*KSCALE); qv[3]=(short)f2bf(aa.w*KSCALE);
      qv[4]=(short)f2bf(bb.x*KSCALE); qv[5]=(short)f2bf(bb.y*KSCALE);
      qv[6]=(short)f2bf(bb.z*KSCALE); qv[7]=(short)f2bf(bb.w*KSCALE);
      qf[h] = qv;
    }
  }

  // prologue: two tiles in flight
  issue(0, smem[0]);
  issue((1 <= qt) ? 1 : 1, smem[1]);     // tile 1 always exists (<=31)

  const v4f zero  = {0.f, 0.f, 0.f, 0.f};
  const v4f minit = {-MB2, -MB2, -MB2, -MB2};
  v4f acc[4];                          // [db]
  acc[0] = zero; acc[1] = zero; acc[2] = zero; acc[3] = zero;
  float l1 = 0.f;

  // diagonal liveness: kq=1 contributes only when qs>=2 at t==qt
  const bool diagLive = (kq * 32 <= qs * 16 + 15);

  int bcur = 0;                          // t % 3, maintained incrementally
  for (int t = 0; t < M; ++t){
    int tn2 = t + 2; if (tn2 > 31) tn2 = 31;       // clamp: tiles 0..31 exist
    int b2 = bcur + 2; if (b2 >= 3) b2 -= 3;       // (t+2) % 3
    issue(tn2, smem[b2]);                           // prefetch 2 tiles ahead
    asm volatile("s_waitcnt vmcnt(4)" ::: "memory"); // tile t landed
    __builtin_amdgcn_s_barrier();
    __builtin_amdgcn_sched_barrier(0);

    if (t < qt || diagLive){
      const char* kbase = smem[bcur];
      const char* vbase = smem[bcur] + 8192;

      const int koff0 = (kq * 4    ) * 1024 + lane * 16;  // kb=2kq,   h=0
      const int koff1 = (kq * 4 + 1) * 1024 + lane * 16;  //           h=1
      const int koff2 = (kq * 4 + 2) * 1024 + lane * 16;  // kb=2kq+1, h=0
      const int koff3 = (kq * 4 + 3) * 1024 + lane * 16;  //           h=1
      v8s kf0 = *(const v8s*)(kbase + koff0);
      v8s kf1 = *(const v8s*)(kbase + koff1);
      v8s kf2 = *(const v8s*)(kbase + koff2);
      v8s kf3 = *(const v8s*)(kbase + koff3);
      v8s vv0 = *(const v8s*)(vbase + koff0);
      v8s vv1 = *(const v8s*)(vbase + koff1);
      v8s vv2 = *(const v8s*)(vbase + koff2);
      v8s vv3 = *(const v8s*)(vbase + koff3);

      // ---- S^T = K * Q^T for my 2 k-subblocks ----
      float p4[2][4];
      __builtin_amdgcn_s_setprio(1);
      {
        v4f st0 = minit, st1 = minit;
        st0 = __builtin_amdgcn_mfma_f32_16x16x32_bf16(kf0, qf[0], st0, 0, 0, 0);
        st1 = __builtin_amdgcn_mfma_f32_16x16x32_bf16(kf2, qf[0], st1, 0, 0, 0);
        st0 = __builtin_amdgcn_mfma_f32_16x16x32_bf16(kf1, qf[1], st0, 0, 0, 0);
        st1 = __builtin_amdgcn_mfma_f32_16x16x32_bf16(kf3, qf[1], st1, 0, 0, 0);
        #pragma unroll
        for (int r = 0; r < 4; ++r){ p4[0][r] = st0[r]; p4[1][r] = st1[r]; }
      }
      __builtin_amdgcn_s_setprio(0);

      if (t == qt){                      // diagonal tile: causal mask
        #pragma unroll
        for (int j = 0; j < 2; ++j)
          #pragma unroll
          for (int r = 0; r < 4; ++r)
            if (kq * 32 + j * 16 + g * 4 + r > qs * 16 + lq) p4[j][r] = -INFINITY;
      }

      // ---- P = exp2(S-4), lane-partial l, pack to bf16 ----
      v4s pf[2];
      #pragma unroll
      for (int j = 0; j < 2; ++j){
        #pragma unroll
        for (int r = 0; r < 4; ++r){
          const float pe = __builtin_amdgcn_exp2f(p4[j][r]);   // masked -> 0
          p4[j][r] = pe;
          l1 += pe;
        }
        unsigned u0, u1;
        asm("v_cvt_pk_bf16_f32 %0, %1, %2" : "=v"(u0) : "v"(p4[j][0]), "v"(p4[j][1]));
        asm("v_cvt_pk_bf16_f32 %0, %1, %2" : "=v"(u1) : "v"(p4[j][2]), "v"(p4[j][3]));
        union { unsigned u[2]; v4s s4; } P; P.u[0] = u0; P.u[1] = u1;
        pf[j] = P.s4;
      }

      // ---- O^T += V^T * P^T for my 2 k-subblocks ----
      __builtin_amdgcn_s_setprio(1);
      {
        v4s va0 = {vv0[0], vv0[1], vv0[2], vv0[3]};
        v4s va1 = {vv0[4], vv0[5], vv0[6], vv0[7]};
        v4s vb0 = {vv1[0], vv1[1], vv1[2], vv1[3]};
        v4s vb1 = {vv1[4], vv1[5], vv1[6], vv1[7]};
        acc[0] = __builtin_amdgcn_mfma_f32_16x16x16bf16_1k(va0, pf[0], acc[0], 0, 0, 0);
        acc[1] = __builtin_amdgcn_mfma_f32_16x16x16bf16_1k(va1, pf[0], acc[1], 0, 0, 0);
        acc[2] = __builtin_amdgcn_mfma_f32_16x16x16bf16_1k(vb0, pf[0], acc[2], 0, 0, 0);
        acc[3] = __builtin_amdgcn_mfma_f32_16x16x16bf16_1k(vb1, pf[0], acc[3], 0, 0, 0);
        v4s vc0 = {vv2[0], vv2[1], vv2[2], vv2[3]};
        v4s vc1 = {vv2[4], vv2[5], vv2[6], vv2[7]};
        v4s vd0 = {vv3[0], vv3[1], vv3[2], vv3[3]};
        v4s vd1 = {vv3[4], vv3[5], vv3[6], vv3[7]};
        acc[0] = __builtin_amdgcn_mfma_f32_16x16x16bf16_1k(vc0, pf[1], acc[0], 0, 0, 0);
        acc[1] = __builtin_amdgcn_mfma_f32_16x16x16bf16_1k(vc1, pf[1], acc[1], 0, 0, 0);
        acc[2] = __builtin_amdgcn_mfma_f32_16x16x16bf16_1k(vd0, pf[1], acc[2], 0, 0, 0);
        acc[3] = __builtin_amdgcn_mfma_f32_16x16x16bf16_1k(vd1, pf[1], acc[3], 0, 0, 0);
      }
      __builtin_amdgcn_s_setprio(0);
    }
    __builtin_amdgcn_s_barrier();
    __builtin_amdgcn_sched_barrier(0);
    ++bcur; if (bcur == 3) bcur = 0;
  }

  // ---- drain async staging writes before reusing smem as scratch ----
  asm volatile("s_waitcnt vmcnt(0)" ::: "memory");
  __builtin_amdgcn_sched_barrier(0);
  __syncthreads();

  // ---- epilogue: 2-way (kq) reduction of l and O, conflict-free layout ----
  l1 += __shfl_xor(l1, 16);
  l1 += __shfl_xor(l1, 32);

  float* Lx = (float*)(smem[1]);         // 64 floats [qs*16 + lq]
  v4f*  Ox = (v4f*)(smem[0]);            // [ (qs*4+db)*64 + lane ] 16KB
  if (kq == 1){
    if (lane < 16) Lx[qs * 16 + lane] = l1;
    #pragma unroll
    for (int db = 0; db < 4; ++db)
      Ox[(qs * 4 + db) * 64 + lane] = acc[db];
  }
  __syncthreads();
  if (kq == 0){
    const float lt   = l1 + Lx[qs * 16 + lq];
    const float invl = 1.f / lt;
    float* Ob = O + ((size_t)bh * S_LEN + qw0 + lq) * DH;
    #pragma unroll
    for (int db = 0; db < 4; ++db){
      v4f o2 = (acc[db] + Ox[(qs * 4 + db) * 64 + lane]) * invl;
      *(v4f*)(Ob + db * 16 + g * 4) = o2;
    }
    if (lane < 16)
      L[(size_t)bh * S_LEN + qw0 + lane] = logf(lt) + MB2 * LN2;
  }
}

// ---------------- naive fallback (only if ws too small) ----------------
__global__ __launch_bounds__(64) void fa_naive(
    const float* __restrict__ Q, const float* __restrict__ K,
    const float* __restrict__ V, float* __restrict__ O, float* __restrict__ L)
{
  const int q  = blockIdx.x;
  const int bh = blockIdx.y;
  const int d  = threadIdx.x;
  const float qv = Q[(size_t)(bh * S_LEN + q) * DH + d];
  float m = -INFINITY, l = 0.f, o = 0.f;
  for (int k = 0; k <= q; ++k){
    float s = qv * K[(size_t)(bh * S_LEN + k) * DH + d];
    #pragma unroll
    for (int off = 32; off > 0; off >>= 1) s += __shfl_xor(s, off);
    s *= 0.125f;
    const float mn = fmaxf(m, s);
    const float sfc = expf(m - mn);
    const float pe = expf(s - mn);
    l = l * sfc + pe;
    o = o * sfc + pe * V[(size_t)(bh * S_LEN + k) * DH + d];
    m = mn;
  }
  O[(size_t)(bh * S_LEN + q) * DH + d] = o / l;
  if (d == 0) L[(size_t)bh * S_LEN + q] = m + logf(l);
}

extern "C" void kernel_launch(void* const* d_in, const int* in_sizes, int n_in,
                              void* d_out, int out_size, void* d_ws, size_t ws_size,
                              hipStream_t stream)
{
  (void)in_sizes; (void)n_in; (void)out_size;
  const float* Q = (const float*)d_in[0];
  const float* K = (const float*)d_in[1];
  const float* V = (const float*)d_in[2];
  float* O = (float*)d_out;
  float* L = O + (size_t)NBH * S_LEN * DH;

  const size_t half = (size_t)NBH * S_LEN * DH * sizeof(unsigned short); // 8 MiB
  if (ws_size >= 2 * half){
    unsigned short* Kf = (unsigned short*)d_ws;
    unsigned short* Vf = Kf + (size_t)NBH * S_LEN * DH;
    prep<<<dim3(S_LEN / 64, NBH), 256, 0, stream>>>(K, V, Kf, Vf);
    fa_fwd<<<dim3(1024), 512, 0, stream>>>(Q, Kf, Vf, O, L);
  } else {
    fa_naive<<<dim3(S_LEN, NBH), 64, 0, stream>>>(Q, K, V, O, L);
  }
}